// Round 1
// baseline (624.489 us; speedup 1.0000x reference)
//
#include <hip/hip_runtime.h>
#include <stdint.h>

typedef __attribute__((ext_vector_type(8))) short bf16x8_t;  // 8 bf16 in 4 VGPRs
typedef __attribute__((ext_vector_type(4))) float f32x4_t;   // MFMA accumulator

#define BM 128
#define BN 128
#define BK 64

// ---------- helpers ----------

__device__ __forceinline__ unsigned short f2bf_rn(float f) {
    unsigned int u = __float_as_uint(f);
    u += 0x7fffu + ((u >> 16) & 1u);   // round-to-nearest-even
    return (unsigned short)(u >> 16);
}

// one packed byte (as int32 in [0,256)) -> two bf16 (q-8), low nibble = even k
__device__ __forceinline__ unsigned int dq2(int v) {
    float f0 = (float)((v & 15) - 8);
    float f1 = (float)(((v >> 4) & 15) - 8);
    // bf16 of small ints is exact: truncation == RN
    return (__float_as_uint(f0) >> 16) | (__float_as_uint(f1) & 0xffff0000u);
}

__device__ __forceinline__ void gload_lds16(const void* g, void* l) {
    __builtin_amdgcn_global_load_lds(
        (__attribute__((address_space(1))) void*)g,
        (__attribute__((address_space(3))) void*)l, 16, 0, 0);
}

// ---------- pre-pass kernels ----------

__global__ void cvt_x_kernel(const float4* __restrict__ x4,
                             ushort4* __restrict__ o4, int n4) {
    int stride = gridDim.x * blockDim.x;
    for (int i = blockIdx.x * blockDim.x + threadIdx.x; i < n4; i += stride) {
        float4 v = x4[i];
        ushort4 o;
        o.x = f2bf_rn(v.x); o.y = f2bf_rn(v.y);
        o.z = f2bf_rn(v.z); o.w = f2bf_rn(v.w);
        o4[i] = o;
    }
}

__global__ void dequant_w_kernel(const int4* __restrict__ pw4,
                                 uint4* __restrict__ o4, int n4) {
    int stride = gridDim.x * blockDim.x;
    for (int i = blockIdx.x * blockDim.x + threadIdx.x; i < n4; i += stride) {
        int4 v = pw4[i];
        uint4 o;
        o.x = dq2(v.x); o.y = dq2(v.y); o.z = dq2(v.z); o.w = dq2(v.w);
        o4[i] = o;
    }
}

// ---------- main GEMM: y[M,N] = Xb[M,K] * Wb[N,K]^T, epilogue *scale[n]+bias[n] ----------
// m97 structure: 128x128 tile, BK=64, 256 threads (4 waves 2x2, each 64x64 via 4x4
// frags of mfma_f32_16x16x32_bf16), global_load_lds width=16 staging.

__global__ __launch_bounds__(256) void qlin_gemm(
    const short* __restrict__ Xb, const short* __restrict__ Wb,
    const float* __restrict__ scales, const float* __restrict__ bias,
    float* __restrict__ Y, int M, int N, int K)
{
    __shared__ short As[BM * BK];
    __shared__ short Bs[BN * BK];

    int nbm = M / BM, nbn = N / BN;
    int nwg = nbm * nbn;
    // bijective XCD swizzle (m204 form)
    int bid = blockIdx.x;
    int q = nwg >> 3, r = nwg & 7;
    int xcd = bid & 7, lid = bid >> 3;
    int wgid = (xcd < r ? xcd * (q + 1) : r * (q + 1) + (xcd - r) * q) + lid;
    int bm = wgid % nbm, bn = wgid / nbm;

    const short* ga = Xb + (size_t)bm * BM * K;
    const short* gb = Wb + (size_t)bn * BN * K;

    int tid = threadIdx.x, lane = tid & 63, wid = tid >> 6;
    int wr = wid >> 1, wc = wid & 1;            // 2x2 wave grid
    int lr = lane >> 3, lc = (lane & 7) * 8;    // staging: row-in-stripe / col
    int fr = lane & 15, fk = (lane >> 4) * 8;   // fragment row / k-offset

    f32x4_t acc[4][4] = {};

    for (int kt = 0; kt < K; kt += BK) {
        #pragma unroll
        for (int i = 0; i < 4; ++i) {
            int rA = i * 32 + wid * 8;          // wave-uniform 8-row stripe
            gload_lds16(ga + (size_t)(rA + lr) * K + kt + lc, &As[rA * BK]);
            gload_lds16(gb + (size_t)(rA + lr) * K + kt + lc, &Bs[rA * BK]);
        }
        __syncthreads();
        #pragma unroll
        for (int ks = 0; ks < 2; ++ks) {
            bf16x8_t a[4], b[4];
            #pragma unroll
            for (int i = 0; i < 4; ++i)
                a[i] = *(const bf16x8_t*)&As[(wr * 64 + i * 16 + fr) * BK + ks * 32 + fk];
            #pragma unroll
            for (int j = 0; j < 4; ++j)
                b[j] = *(const bf16x8_t*)&Bs[(wc * 64 + j * 16 + fr) * BK + ks * 32 + fk];
            #pragma unroll
            for (int i = 0; i < 4; ++i)
                #pragma unroll
                for (int j = 0; j < 4; ++j)
                    acc[i][j] = __builtin_amdgcn_mfma_f32_16x16x32_bf16(
                        a[i], b[j], acc[i][j], 0, 0, 0);
        }
        __syncthreads();
    }

    int row_base = bm * BM + wr * 64;
    int col_base = bn * BN + wc * 64;
    #pragma unroll
    for (int j = 0; j < 4; ++j) {
        int n = col_base + j * 16 + fr;
        float sc = scales[n], bi = bias[n];
        #pragma unroll
        for (int i = 0; i < 4; ++i) {
            int m0 = row_base + i * 16 + (lane >> 4) * 4;
            #pragma unroll
            for (int r2 = 0; r2 < 4; ++r2)
                Y[(size_t)(m0 + r2) * N + n] = acc[i][j][r2] * sc + bi;
        }
    }
}

// ---------- fallback (if ws too small): simple tiled fp32, inline dequant ----------

__global__ __launch_bounds__(256) void qlin_fallback(
    const float* __restrict__ x, const int* __restrict__ pw,
    const float* __restrict__ scales, const float* __restrict__ bias,
    float* __restrict__ Y, int M, int N, int K)
{
    __shared__ float Xs[64][32];
    __shared__ float Ws[64][33];
    int bn = blockIdx.x, bm = blockIdx.y;
    int tid = threadIdx.x;
    int tr = tid >> 4, tc = tid & 15;
    float acc[4][4] = {};
    int K2 = K >> 1;
    for (int kt = 0; kt < K; kt += 32) {
        #pragma unroll
        for (int u = 0; u < 8; ++u) {
            int idx = u * 256 + tid;
            int rr = idx >> 5, cc = idx & 31;
            Xs[rr][cc] = x[(size_t)(bm * 64 + rr) * K + kt + cc];
        }
        #pragma unroll
        for (int u = 0; u < 4; ++u) {
            int idx = u * 256 + tid;
            int rr = idx >> 4, cc = idx & 15;
            int v = pw[(size_t)(bn * 64 + rr) * K2 + (kt >> 1) + cc];
            Ws[rr][cc * 2]     = (float)((v & 15) - 8);
            Ws[rr][cc * 2 + 1] = (float)(((v >> 4) & 15) - 8);
        }
        __syncthreads();
        #pragma unroll 8
        for (int kk = 0; kk < 32; ++kk) {
            float xv[4], wv[4];
            #pragma unroll
            for (int i = 0; i < 4; ++i) xv[i] = Xs[tr * 4 + i][kk];
            #pragma unroll
            for (int j = 0; j < 4; ++j) wv[j] = Ws[tc * 4 + j][kk];
            #pragma unroll
            for (int i = 0; i < 4; ++i)
                #pragma unroll
                for (int j = 0; j < 4; ++j)
                    acc[i][j] += xv[i] * wv[j];
        }
        __syncthreads();
    }
    #pragma unroll
    for (int j = 0; j < 4; ++j) {
        int n = bn * 64 + tc * 4 + j;
        float sc = scales[n], bi = bias[n];
        #pragma unroll
        for (int i = 0; i < 4; ++i) {
            int m = bm * 64 + tr * 4 + i;
            Y[(size_t)m * N + n] = acc[i][j] * sc + bi;
        }
    }
}

// ---------- host ----------

extern "C" void kernel_launch(void* const* d_in, const int* in_sizes, int n_in,
                              void* d_out, int out_size, void* d_ws, size_t ws_size,
                              hipStream_t stream) {
    const float* x      = (const float*)d_in[0];
    const int*   pw     = (const int*)d_in[1];
    const float* scales = (const float*)d_in[2];
    const float* bias   = (const float*)d_in[3];
    float*       y      = (float*)d_out;

    int N = in_sizes[2];                         // 11008
    long long pwe = in_sizes[1];                 // N*K/2
    int K = (int)((2 * pwe) / N);                // 4096
    int M = in_sizes[0] / K;                     // 4096

    size_t xb_bytes = (size_t)M * K * 2;
    size_t wb_bytes = (size_t)N * K * 2;

    if (ws_size >= xb_bytes + wb_bytes) {
        short* xb = (short*)d_ws;
        short* wb = (short*)((char*)d_ws + xb_bytes);
        int n4x = (M * K) / 4;
        hipLaunchKernelGGL(cvt_x_kernel, dim3(2048), dim3(256), 0, stream,
                           (const float4*)x, (ushort4*)xb, n4x);
        int n4w = (int)(pwe / 4);
        hipLaunchKernelGGL(dequant_w_kernel, dim3(2048), dim3(256), 0, stream,
                           (const int4*)pw, (uint4*)wb, n4w);
        int nwg = (M / BM) * (N / BN);
        hipLaunchKernelGGL(qlin_gemm, dim3(nwg), dim3(256), 0, stream,
                           xb, wb, scales, bias, y, M, N, K);
    } else {
        hipLaunchKernelGGL(qlin_fallback, dim3(N / 64, M / 64), dim3(256), 0, stream,
                           x, pw, scales, bias, y, M, N, K);
    }
}

// Round 2
// 592.308 us; speedup vs baseline: 1.0543x; 1.0543x over previous
//
#include <hip/hip_runtime.h>
#include <stdint.h>

typedef __attribute__((ext_vector_type(8))) short bf16x8_t;  // 8 bf16 in 4 VGPRs
typedef __attribute__((ext_vector_type(4))) float f32x4_t;   // MFMA accumulator

#define BM 128
#define BN 128
#define BK 64

// ---------- helpers ----------

__device__ __forceinline__ unsigned short f2bf_rn(float f) {
    unsigned int u = __float_as_uint(f);
    u += 0x7fffu + ((u >> 16) & 1u);   // round-to-nearest-even
    return (unsigned short)(u >> 16);
}

// one packed byte (as int32 in [0,256)) -> two bf16 (q-8), low nibble = even k
__device__ __forceinline__ unsigned int dq2(int v) {
    float f0 = (float)((v & 15) - 8);
    float f1 = (float)(((v >> 4) & 15) - 8);
    // bf16 of small ints is exact: truncation == RN
    return (__float_as_uint(f0) >> 16) | (__float_as_uint(f1) & 0xffff0000u);
}

__device__ __forceinline__ void gload_lds16(const void* g, void* l) {
    __builtin_amdgcn_global_load_lds(
        (__attribute__((address_space(1))) void*)g,
        (__attribute__((address_space(3))) void*)l, 16, 0, 0);
}

// ---------- pre-pass kernels ----------
// Both write the bf16 buffers PRE-SWIZZLED: within each row, 16B chunk c is
// stored at chunk index c ^ (row & 7) (involution, permutes within each 128B
// group). GEMM stages linearly with global_load_lds, so LDS inherits the
// swizzle; fragment ds_reads XOR the chunk index -> conflict-free (all 32
// banks covered instead of 16-way aliasing at 128B row stride).

__global__ void cvt_x_kernel(const float4* __restrict__ x4,
                             uint4* __restrict__ o4, int nchunks, int cpr) {
    int stride = gridDim.x * blockDim.x;
    for (int i = blockIdx.x * blockDim.x + threadIdx.x; i < nchunks; i += stride) {
        int r = i / cpr, c = i - r * cpr;
        float4 v0 = x4[2 * i];
        float4 v1 = x4[2 * i + 1];
        uint4 o;
        o.x = (unsigned)f2bf_rn(v0.x) | ((unsigned)f2bf_rn(v0.y) << 16);
        o.y = (unsigned)f2bf_rn(v0.z) | ((unsigned)f2bf_rn(v0.w) << 16);
        o.z = (unsigned)f2bf_rn(v1.x) | ((unsigned)f2bf_rn(v1.y) << 16);
        o.w = (unsigned)f2bf_rn(v1.z) | ((unsigned)f2bf_rn(v1.w) << 16);
        o4[r * cpr + (c ^ (r & 7))] = o;
    }
}

__global__ void dequant_w_kernel(const int4* __restrict__ pw4,
                                 uint4* __restrict__ o4, int nchunks, int cpr) {
    int stride = gridDim.x * blockDim.x;
    for (int i = blockIdx.x * blockDim.x + threadIdx.x; i < nchunks; i += stride) {
        int r = i / cpr, c = i - r * cpr;
        int4 v = pw4[i];
        uint4 o;
        o.x = dq2(v.x); o.y = dq2(v.y); o.z = dq2(v.z); o.w = dq2(v.w);
        o4[r * cpr + (c ^ (r & 7))] = o;
    }
}

// ---------- main GEMM: y[M,N] = Xb[M,K] * Wb[N,K]^T, epilogue *scale[n]+bias[n] ----------
// m97 structure: 128x128 tile, BK=64, 256 threads (4 waves 2x2, each 64x64 via 4x4
// frags of mfma_f32_16x16x32_bf16), global_load_lds width=16 staging.
// LDS layout is XOR-swizzled via the pre-swizzled global buffers (see above).

__global__ __launch_bounds__(256) void qlin_gemm(
    const short* __restrict__ Xb, const short* __restrict__ Wb,
    const float* __restrict__ scales, const float* __restrict__ bias,
    float* __restrict__ Y, int M, int N, int K)
{
    __shared__ short As[BM * BK];
    __shared__ short Bs[BN * BK];

    int nbm = M / BM, nbn = N / BN;
    int nwg = nbm * nbn;
    // bijective XCD swizzle (m204 form)
    int bid = blockIdx.x;
    int q = nwg >> 3, r = nwg & 7;
    int xcd = bid & 7, lid = bid >> 3;
    int wgid = (xcd < r ? xcd * (q + 1) : r * (q + 1) + (xcd - r) * q) + lid;
    int bm = wgid % nbm, bn = wgid / nbm;

    const short* ga = Xb + (size_t)bm * BM * K;
    const short* gb = Wb + (size_t)bn * BN * K;

    int tid = threadIdx.x, lane = tid & 63, wid = tid >> 6;
    int wr = wid >> 1, wc = wid & 1;            // 2x2 wave grid
    int lr = lane >> 3, lc = (lane & 7) * 8;    // staging: row-in-stripe / col
    int fr = lane & 15;                          // fragment row
    int fc = lane >> 4;                          // fragment k-chunk (8 bf16 units)

    f32x4_t acc[4][4] = {};

    for (int kt = 0; kt < K; kt += BK) {
        #pragma unroll
        for (int i = 0; i < 4; ++i) {
            int rA = i * 32 + wid * 8;          // wave-uniform 8-row stripe
            gload_lds16(ga + (size_t)(rA + lr) * K + kt + lc, &As[rA * BK]);
            gload_lds16(gb + (size_t)(rA + lr) * K + kt + lc, &Bs[rA * BK]);
        }
        __syncthreads();
        #pragma unroll
        for (int ks = 0; ks < 2; ++ks) {
            bf16x8_t a[4], b[4];
            #pragma unroll
            for (int i = 0; i < 4; ++i) {
                int ar = wr * 64 + i * 16 + fr;
                int ch = (ks * 4 + fc) ^ (ar & 7);
                a[i] = *(const bf16x8_t*)&As[ar * BK + ch * 8];
            }
            #pragma unroll
            for (int j = 0; j < 4; ++j) {
                int br = wc * 64 + j * 16 + fr;
                int ch = (ks * 4 + fc) ^ (br & 7);
                b[j] = *(const bf16x8_t*)&Bs[br * BK + ch * 8];
            }
            #pragma unroll
            for (int i = 0; i < 4; ++i)
                #pragma unroll
                for (int j = 0; j < 4; ++j)
                    acc[i][j] = __builtin_amdgcn_mfma_f32_16x16x32_bf16(
                        a[i], b[j], acc[i][j], 0, 0, 0);
        }
        __syncthreads();
    }

    int row_base = bm * BM + wr * 64;
    int col_base = bn * BN + wc * 64;
    #pragma unroll
    for (int j = 0; j < 4; ++j) {
        int n = col_base + j * 16 + fr;
        float sc = scales[n], bi = bias[n];
        #pragma unroll
        for (int i = 0; i < 4; ++i) {
            int m0 = row_base + i * 16 + (lane >> 4) * 4;
            #pragma unroll
            for (int r2 = 0; r2 < 4; ++r2)
                Y[(size_t)(m0 + r2) * N + n] = acc[i][j][r2] * sc + bi;
        }
    }
}

// ---------- fallback (if ws too small): simple tiled fp32, inline dequant ----------

__global__ __launch_bounds__(256) void qlin_fallback(
    const float* __restrict__ x, const int* __restrict__ pw,
    const float* __restrict__ scales, const float* __restrict__ bias,
    float* __restrict__ Y, int M, int N, int K)
{
    __shared__ float Xs[64][32];
    __shared__ float Ws[64][33];
    int bn = blockIdx.x, bm = blockIdx.y;
    int tid = threadIdx.x;
    int tr = tid >> 4, tc = tid & 15;
    float acc[4][4] = {};
    int K2 = K >> 1;
    for (int kt = 0; kt < K; kt += 32) {
        #pragma unroll
        for (int u = 0; u < 8; ++u) {
            int idx = u * 256 + tid;
            int rr = idx >> 5, cc = idx & 31;
            Xs[rr][cc] = x[(size_t)(bm * 64 + rr) * K + kt + cc];
        }
        #pragma unroll
        for (int u = 0; u < 4; ++u) {
            int idx = u * 256 + tid;
            int rr = idx >> 4, cc = idx & 15;
            int v = pw[(size_t)(bn * 64 + rr) * K2 + (kt >> 1) + cc];
            Ws[rr][cc * 2]     = (float)((v & 15) - 8);
            Ws[rr][cc * 2 + 1] = (float)(((v >> 4) & 15) - 8);
        }
        __syncthreads();
        #pragma unroll 8
        for (int kk = 0; kk < 32; ++kk) {
            float xv[4], wv[4];
            #pragma unroll
            for (int i = 0; i < 4; ++i) xv[i] = Xs[tr * 4 + i][kk];
            #pragma unroll
            for (int j = 0; j < 4; ++j) wv[j] = Ws[tc * 4 + j][kk];
            #pragma unroll
            for (int i = 0; i < 4; ++i)
                #pragma unroll
                for (int j = 0; j < 4; ++j)
                    acc[i][j] += xv[i] * wv[j];
        }
        __syncthreads();
    }
    #pragma unroll
    for (int j = 0; j < 4; ++j) {
        int n = bn * 64 + tc * 4 + j;
        float sc = scales[n], bi = bias[n];
        #pragma unroll
        for (int i = 0; i < 4; ++i) {
            int m = bm * 64 + tr * 4 + i;
            Y[(size_t)m * N + n] = acc[i][j] * sc + bi;
        }
    }
}

// ---------- host ----------

extern "C" void kernel_launch(void* const* d_in, const int* in_sizes, int n_in,
                              void* d_out, int out_size, void* d_ws, size_t ws_size,
                              hipStream_t stream) {
    const float* x      = (const float*)d_in[0];
    const int*   pw     = (const int*)d_in[1];
    const float* scales = (const float*)d_in[2];
    const float* bias   = (const float*)d_in[3];
    float*       y      = (float*)d_out;

    int N = in_sizes[2];                         // 11008
    long long pwe = in_sizes[1];                 // N*K/2
    int K = (int)((2 * pwe) / N);                // 4096
    int M = in_sizes[0] / K;                     // 4096

    size_t xb_bytes = (size_t)M * K * 2;
    size_t wb_bytes = (size_t)N * K * 2;

    if (ws_size >= xb_bytes + wb_bytes) {
        short* xb = (short*)d_ws;
        short* wb = (short*)((char*)d_ws + xb_bytes);
        int cpr = K / 8;                         // 16B chunks per row
        int ncx = (M * K) / 8;
        hipLaunchKernelGGL(cvt_x_kernel, dim3(2048), dim3(256), 0, stream,
                           (const float4*)x, (uint4*)xb, ncx, cpr);
        int ncw = (int)(pwe / 4);                // = N*K/8
        hipLaunchKernelGGL(dequant_w_kernel, dim3(2048), dim3(256), 0, stream,
                           (const int4*)pw, (uint4*)wb, ncw, cpr);
        int nwg = (M / BM) * (N / BN);
        hipLaunchKernelGGL(qlin_gemm, dim3(nwg), dim3(256), 0, stream,
                           xb, wb, scales, bias, y, M, N, K);
    } else {
        hipLaunchKernelGGL(qlin_fallback, dim3(N / 64, M / 64), dim3(256), 0, stream,
                           x, pw, scales, bias, y, M, N, K);
    }
}

// Round 3
// 547.138 us; speedup vs baseline: 1.1414x; 1.0826x over previous
//
#include <hip/hip_runtime.h>
#include <stdint.h>

typedef __attribute__((ext_vector_type(8))) short bf16x8_t;  // 8 bf16 in 4 VGPRs
typedef __attribute__((ext_vector_type(4))) float f32x4_t;   // MFMA accumulator

#define BM2 256
#define BN2 256
#define BK2 64

// ---------- helpers ----------

__device__ __forceinline__ unsigned short f2bf_rn(float f) {
    unsigned int u = __float_as_uint(f);
    u += 0x7fffu + ((u >> 16) & 1u);   // round-to-nearest-even
    return (unsigned short)(u >> 16);
}

// one packed byte (as int32 in [0,256)) -> two bf16 (q-8), low nibble = even k
__device__ __forceinline__ unsigned int dq2(int v) {
    float f0 = (float)((v & 15) - 8);
    float f1 = (float)(((v >> 4) & 15) - 8);
    return (__float_as_uint(f0) >> 16) | (__float_as_uint(f1) & 0xffff0000u);
}

__device__ __forceinline__ void gload_lds16(const void* g, void* l) {
    __builtin_amdgcn_global_load_lds(
        (__attribute__((address_space(1))) void*)g,
        (__attribute__((address_space(3))) void*)l, 16, 0, 0);
}

// ---------- pre-pass kernels ----------
// Write bf16 buffers PRE-SWIZZLED: within each row, 16B chunk c stored at
// c ^ (row & 7) (involution within each 128B group). GEMM stages linearly
// with global_load_lds; fragment ds_reads XOR the chunk index ->
// conflict-free (verified R2: SQ_LDS_BANK_CONFLICT 1.35e8 -> 0).

__global__ void cvt_x_kernel(const float4* __restrict__ x4,
                             uint4* __restrict__ o4, int nchunks, int cpr) {
    int stride = gridDim.x * blockDim.x;
    for (int i = blockIdx.x * blockDim.x + threadIdx.x; i < nchunks; i += stride) {
        int r = i / cpr, c = i - r * cpr;
        float4 v0 = x4[2 * i];
        float4 v1 = x4[2 * i + 1];
        uint4 o;
        o.x = (unsigned)f2bf_rn(v0.x) | ((unsigned)f2bf_rn(v0.y) << 16);
        o.y = (unsigned)f2bf_rn(v0.z) | ((unsigned)f2bf_rn(v0.w) << 16);
        o.z = (unsigned)f2bf_rn(v1.x) | ((unsigned)f2bf_rn(v1.y) << 16);
        o.w = (unsigned)f2bf_rn(v1.z) | ((unsigned)f2bf_rn(v1.w) << 16);
        o4[r * cpr + (c ^ (r & 7))] = o;
    }
}

__global__ void dequant_w_kernel(const int4* __restrict__ pw4,
                                 uint4* __restrict__ o4, int nchunks, int cpr) {
    int stride = gridDim.x * blockDim.x;
    for (int i = blockIdx.x * blockDim.x + threadIdx.x; i < nchunks; i += stride) {
        int r = i / cpr, c = i - r * cpr;
        int4 v = pw4[i];
        uint4 o;
        o.x = dq2(v.x); o.y = dq2(v.y); o.z = dq2(v.z); o.w = dq2(v.w);
        o4[r * cpr + (c ^ (r & 7))] = o;
    }
}

// ---------- main GEMM: 256x256 8-wave 4-phase counted-vmcnt (T2+T3+T4+T5) ----
// y[M,N] = Xb[M,K] * Wb[N,K]^T, epilogue *scale[n]+bias[n].
// 512 thr = 8 waves in 2(M)x4(N) grid; per-wave output 128x64 = acc[8][4].
// LDS 128 KiB: A,B 256x64 bf16, double-buffered. Staging: all 8
// global_load_lds for tile t+1 issued at tile top; s_waitcnt vmcnt(8) keeps
// them in flight while guaranteeing tile t landed (T4: never drain to 0 in
// the main loop). Raw s_barrier (NOT __syncthreads -> would re-drain vmcnt).
// Phases: ph0 reads all B (8xb128) + A m-pair (4), ph1-3 read 4 A each;
// lgkmcnt(0)+sched_barrier(0) [rule #18] then setprio(1) around 16 MFMA (T5).

__global__ __launch_bounds__(512) void qlin_gemm256(
    const short* __restrict__ Xb, const short* __restrict__ Wb,
    const float* __restrict__ scales, const float* __restrict__ bias,
    float* __restrict__ Y, int M, int N, int K)
{
    __shared__ short As[2][BM2 * BK2];
    __shared__ short Bs[2][BN2 * BK2];

    int nbm = M / BM2, nbn = N / BN2;
    int nwg = nbm * nbn;
    // bijective XCD swizzle (m204 form)
    int bid = blockIdx.x;
    int q8 = nwg >> 3, r8 = nwg & 7;
    int xcd = bid & 7, lid = bid >> 3;
    int wgid = (xcd < r8 ? xcd * (q8 + 1) : r8 * (q8 + 1) + (xcd - r8) * q8) + lid;
    int bm = wgid % nbm, bn = wgid / nbm;

    const short* ga = Xb + (size_t)bm * BM2 * K;
    const short* gb = Wb + (size_t)bn * BN2 * K;

    int tid = threadIdx.x, lane = tid & 63, wid = tid >> 6;
    int wr = wid >> 2, wc = wid & 3;            // 2x4 wave grid
    int lr = lane >> 3, lc8 = (lane & 7) * 8;   // staging: row-in-stripe / col
    int fr = lane & 15, fq = lane >> 4;         // frag row / k-quarter

    f32x4_t acc[8][4] = {};

    int nt = K / BK2;
    int cur = 0;

    // prologue: stage tile 0 into buffer 0 (8 loads/thread total: 4 A + 4 B)
    #pragma unroll
    for (int i = 0; i < 4; ++i) {
        int s = wid * 4 + i;                    // 0..31 wave-uniform stripe id
        int r0 = s * 8;
        gload_lds16(ga + (size_t)(r0 + lr) * K + lc8, &As[0][r0 * BK2]);
        gload_lds16(gb + (size_t)(r0 + lr) * K + lc8, &Bs[0][r0 * BK2]);
    }

    for (int t = 0; t < nt; ++t) {
        if (t + 1 < nt) {
            int kt = (t + 1) * BK2;
            #pragma unroll
            for (int i = 0; i < 4; ++i) {
                int s = wid * 4 + i;
                int r0 = s * 8;
                gload_lds16(ga + (size_t)(r0 + lr) * K + kt + lc8, &As[cur ^ 1][r0 * BK2]);
                gload_lds16(gb + (size_t)(r0 + lr) * K + kt + lc8, &Bs[cur ^ 1][r0 * BK2]);
            }
            // wait tile t's 8 loads; tile t+1's 8 stay in flight across barrier
            asm volatile("s_waitcnt vmcnt(8)" ::: "memory");
        } else {
            asm volatile("s_waitcnt vmcnt(0)" ::: "memory");
        }
        __builtin_amdgcn_s_barrier();

        const short* A0 = &As[cur][0];
        const short* B0 = &Bs[cur][0];

        // all B frags for this wave's 64 cols, kept in regs across phases
        bf16x8_t bfr[4][2];
        #pragma unroll
        for (int n = 0; n < 4; ++n)
            #pragma unroll
            for (int ks = 0; ks < 2; ++ks) {
                int row = wc * 64 + n * 16 + fr;
                int kc = ks * 4 + fq;
                bfr[n][ks] = *(const bf16x8_t*)&B0[row * BK2 + ((kc ^ (row & 7)) * 8)];
            }

        #pragma unroll
        for (int ph = 0; ph < 4; ++ph) {
            bf16x8_t afr[2][2];
            #pragma unroll
            for (int mi = 0; mi < 2; ++mi)
                #pragma unroll
                for (int ks = 0; ks < 2; ++ks) {
                    int row = wr * 128 + (ph * 2 + mi) * 16 + fr;
                    int kc = ks * 4 + fq;
                    afr[mi][ks] = *(const bf16x8_t*)&A0[row * BK2 + ((kc ^ (row & 7)) * 8)];
                }
            asm volatile("s_waitcnt lgkmcnt(0)" ::: "memory");
            __builtin_amdgcn_sched_barrier(0);
            __builtin_amdgcn_s_setprio(1);
            #pragma unroll
            for (int mi = 0; mi < 2; ++mi)
                #pragma unroll
                for (int n = 0; n < 4; ++n)
                    #pragma unroll
                    for (int ks = 0; ks < 2; ++ks)
                        acc[ph * 2 + mi][n] = __builtin_amdgcn_mfma_f32_16x16x32_bf16(
                            afr[mi][ks], bfr[n][ks], acc[ph * 2 + mi][n], 0, 0, 0);
            __builtin_amdgcn_s_setprio(0);
            __builtin_amdgcn_s_barrier();
        }
        cur ^= 1;
    }

    int row_base = bm * BM2 + wr * 128;
    int col_base = bn * BN2 + wc * 64;
    #pragma unroll
    for (int n = 0; n < 4; ++n) {
        int col = col_base + n * 16 + fr;
        float sc = scales[col], bi = bias[col];
        #pragma unroll
        for (int m = 0; m < 8; ++m) {
            int m0 = row_base + m * 16 + fq * 4;
            #pragma unroll
            for (int r2 = 0; r2 < 4; ++r2)
                Y[(size_t)(m0 + r2) * N + col] = acc[m][n][r2] * sc + bi;
        }
    }
}

// ---------- fallback (if ws too small): simple tiled fp32, inline dequant ----------

__global__ __launch_bounds__(256) void qlin_fallback(
    const float* __restrict__ x, const int* __restrict__ pw,
    const float* __restrict__ scales, const float* __restrict__ bias,
    float* __restrict__ Y, int M, int N, int K)
{
    __shared__ float Xs[64][32];
    __shared__ float Ws[64][33];
    int bn = blockIdx.x, bm = blockIdx.y;
    int tid = threadIdx.x;
    int tr = tid >> 4, tc = tid & 15;
    float acc[4][4] = {};
    int K2 = K >> 1;
    for (int kt = 0; kt < K; kt += 32) {
        #pragma unroll
        for (int u = 0; u < 8; ++u) {
            int idx = u * 256 + tid;
            int rr = idx >> 5, cc = idx & 31;
            Xs[rr][cc] = x[(size_t)(bm * 64 + rr) * K + kt + cc];
        }
        #pragma unroll
        for (int u = 0; u < 4; ++u) {
            int idx = u * 256 + tid;
            int rr = idx >> 4, cc = idx & 15;
            int v = pw[(size_t)(bn * 64 + rr) * K2 + (kt >> 1) + cc];
            Ws[rr][cc * 2]     = (float)((v & 15) - 8);
            Ws[rr][cc * 2 + 1] = (float)(((v >> 4) & 15) - 8);
        }
        __syncthreads();
        #pragma unroll 8
        for (int kk = 0; kk < 32; ++kk) {
            float xv[4], wv[4];
            #pragma unroll
            for (int i = 0; i < 4; ++i) xv[i] = Xs[tr * 4 + i][kk];
            #pragma unroll
            for (int j = 0; j < 4; ++j) wv[j] = Ws[tc * 4 + j][kk];
            #pragma unroll
            for (int i = 0; i < 4; ++i)
                #pragma unroll
                for (int j = 0; j < 4; ++j)
                    acc[i][j] += xv[i] * wv[j];
        }
        __syncthreads();
    }
    #pragma unroll
    for (int j = 0; j < 4; ++j) {
        int n = bn * 64 + tc * 4 + j;
        float sc = scales[n], bi = bias[n];
        #pragma unroll
        for (int i = 0; i < 4; ++i) {
            int m = bm * 64 + tr * 4 + i;
            Y[(size_t)m * N + n] = acc[i][j] * sc + bi;
        }
    }
}

// ---------- host ----------

extern "C" void kernel_launch(void* const* d_in, const int* in_sizes, int n_in,
                              void* d_out, int out_size, void* d_ws, size_t ws_size,
                              hipStream_t stream) {
    const float* x      = (const float*)d_in[0];
    const int*   pw     = (const int*)d_in[1];
    const float* scales = (const float*)d_in[2];
    const float* bias   = (const float*)d_in[3];
    float*       y      = (float*)d_out;

    int N = in_sizes[2];                         // 11008
    long long pwe = in_sizes[1];                 // N*K/2
    int K = (int)((2 * pwe) / N);                // 4096
    int M = in_sizes[0] / K;                     // 4096

    size_t xb_bytes = (size_t)M * K * 2;
    size_t wb_bytes = (size_t)N * K * 2;

    bool fits = (ws_size >= xb_bytes + wb_bytes);
    bool dims_ok = (M % BM2 == 0) && (N % BN2 == 0) && (K % BK2 == 0) && (K % 8 == 0);

    if (fits && dims_ok) {
        short* xb = (short*)d_ws;
        short* wb = (short*)((char*)d_ws + xb_bytes);
        int cpr = K / 8;                         // 16B chunks per row
        int ncx = (M * K) / 8;
        hipLaunchKernelGGL(cvt_x_kernel, dim3(2048), dim3(256), 0, stream,
                           (const float4*)x, (uint4*)xb, ncx, cpr);
        int ncw = (int)(pwe / 4);                // = N*K/8
        hipLaunchKernelGGL(dequant_w_kernel, dim3(2048), dim3(256), 0, stream,
                           (const int4*)pw, (uint4*)wb, ncw, cpr);
        int nwg = (M / BM2) * (N / BN2);
        hipLaunchKernelGGL(qlin_gemm256, dim3(nwg), dim3(512), 0, stream,
                           xb, wb, scales, bias, y, M, N, K);
    } else {
        hipLaunchKernelGGL(qlin_fallback, dim3(N / 64, M / 64), dim3(256), 0, stream,
                           x, pw, scales, bias, y, M, N, K);
    }
}

// Round 4
// 456.465 us; speedup vs baseline: 1.3681x; 1.1986x over previous
//
#include <hip/hip_runtime.h>
#include <stdint.h>

typedef __attribute__((ext_vector_type(8))) short bf16x8_t;  // 8 bf16 in 4 VGPRs
typedef __attribute__((ext_vector_type(4))) float f32x4_t;   // MFMA accumulator

#define BM2 256
#define BN2 256
#define BK2 64

// ---------- helpers ----------

__device__ __forceinline__ unsigned short f2bf_rn(float f) {
    unsigned int u = __float_as_uint(f);
    u += 0x7fffu + ((u >> 16) & 1u);   // round-to-nearest-even
    return (unsigned short)(u >> 16);
}

// one packed byte (as int32 in [0,256)) -> two bf16 (q-8), low nibble = even k
__device__ __forceinline__ unsigned int dq2(int v) {
    float f0 = (float)((v & 15) - 8);
    float f1 = (float)(((v >> 4) & 15) - 8);
    return (__float_as_uint(f0) >> 16) | (__float_as_uint(f1) & 0xffff0000u);
}

__device__ __forceinline__ void gload_lds16(const void* g, void* l) {
    __builtin_amdgcn_global_load_lds(
        (__attribute__((address_space(1))) void*)g,
        (__attribute__((address_space(3))) void*)l, 16, 0, 0);
}

// ---------- pre-pass kernels: emit TILED kq-major bf16 layout ----------
// Dest layout (16B chunks): [rowblk256][kt(K/64)][kq(4)][slot(512)]
//   slot = (row&255)*2 + chp,  chp = (kc&1) ^ ((row>>2)&1)   (bank swizzle)
// Each kq block (8 KB) is CONTIGUOUS -> GEMM stages it with 512 threads x 16B
// perfectly linearly via global_load_lds; fragment ds_reads use
// chp = (fq&1)^((fr>>2)&1) (lane-constant) -> 2-way banks = conflict-free.

__device__ __forceinline__ int tiled_dest(int r, int kc, int nkt) {
    int rb = r & 255;
    int kt = kc >> 3, kcl = kc & 7;
    int kq = kcl >> 1, ch = kcl & 1;
    int chp = ch ^ ((rb >> 2) & 1);
    return ((((r >> 8) * nkt + kt) * 4 + kq) << 9) + rb * 2 + chp;
}

__global__ void cvt_x_kernel(const float4* __restrict__ x4,
                             uint4* __restrict__ o4, int nchunks, int cpr, int nkt) {
    int stride = gridDim.x * blockDim.x;
    for (int i = blockIdx.x * blockDim.x + threadIdx.x; i < nchunks; i += stride) {
        int r = i / cpr, kc = i - r * cpr;
        float4 v0 = x4[2 * i];
        float4 v1 = x4[2 * i + 1];
        uint4 o;
        o.x = (unsigned)f2bf_rn(v0.x) | ((unsigned)f2bf_rn(v0.y) << 16);
        o.y = (unsigned)f2bf_rn(v0.z) | ((unsigned)f2bf_rn(v0.w) << 16);
        o.z = (unsigned)f2bf_rn(v1.x) | ((unsigned)f2bf_rn(v1.y) << 16);
        o.w = (unsigned)f2bf_rn(v1.z) | ((unsigned)f2bf_rn(v1.w) << 16);
        o4[tiled_dest(r, kc, nkt)] = o;
    }
}

__global__ void dequant_w_kernel(const int4* __restrict__ pw4,
                                 uint4* __restrict__ o4, int nchunks, int cpr, int nkt) {
    int stride = gridDim.x * blockDim.x;
    for (int i = blockIdx.x * blockDim.x + threadIdx.x; i < nchunks; i += stride) {
        int r = i / cpr, kc = i - r * cpr;
        int4 v = pw4[i];
        uint4 o;
        o.x = dq2(v.x); o.y = dq2(v.y); o.z = dq2(v.z); o.w = dq2(v.w);
        o4[tiled_dest(r, kc, nkt)] = o;
    }
}

// ---------- main GEMM: 256x256x64, 8 waves, K-sliced 2-phase counted-vmcnt ----
// Per tile: 2 phases. Phase p: issue next tile's K-half p (4 gload_lds,
// linear 8KB blocks) -> vmcnt(8) [never 0 in main loop; each group has 2 full
// phases of latency slack] -> s_barrier -> 12 ds_read_b128 + 32 MFMA
// (compiler-scheduled interleave; no lgkm fences, no intra-phase barriers).
// Race ledger: RAW: per-wave vmcnt(8) retires exactly this phase's group,
// barrier joins all waves. WAR: group read at tile u phase p is consumed
// (lgkm-retired into MFMAs) before u.ph(p+1)'s barrier; its overwrite is
// issued at u+1.ph(p), i.e. >= 2 barriers later. Buffers: tile t in buf[t&1].

__global__ __launch_bounds__(512) void qlin_gemm256(
    const short* __restrict__ Xb, const short* __restrict__ Wb,
    const float* __restrict__ scales, const float* __restrict__ bias,
    float* __restrict__ Y, int M, int N, int K)
{
    __shared__ short As[2][4][4096];   // [buf][kq][512 slots x 8 shorts] = 64 KB
    __shared__ short Bs[2][4][4096];   // 64 KB

    int nbm = M >> 8, nbn = N >> 8, nkt = K >> 6;
    int nwg = nbm * nbn;
    // bijective XCD swizzle (m204 form)
    int bid = blockIdx.x;
    int q8 = nwg >> 3, r8 = nwg & 7;
    int xcd = bid & 7, lid = bid >> 3;
    int wgid = (xcd < r8 ? xcd * (q8 + 1) : r8 * (q8 + 1) + (xcd - r8) * q8) + lid;
    int bm = wgid % nbm, bn = wgid / nbm;

    const short* ga = Xb + (size_t)bm * nkt * 16384;   // nkt*4 kq-blocks x 4096 shorts
    const short* gb = Wb + (size_t)bn * nkt * 16384;

    int tid = threadIdx.x, lane = tid & 63, wid = tid >> 6;
    int wr = wid >> 2, wc = wid & 3;          // 2x4 wave grid, per-wave out 128x64
    int fr = lane & 15, fq = lane >> 4;       // frag row / k-subchunk
    int chp = (fq & 1) ^ ((fr >> 2) & 1);     // lane-constant chunk swizzle

    f32x4_t acc[8][4] = {};

    int nt = nkt;

    // lsel: offset within a 2-kq phase pair (shorts): kq-local + row-chunk
    int lsel = (fq >> 1) * 4096 + fr * 16 + chp * 8;
    int arow = wr * 2048;                     // (wr*128 rows)*16 shorts
    int brow = wc * 1024;                     // (wc*64 rows)*16 shorts

#define STAGE(tt, h)                                                          \
    do {                                                                      \
        int blk_ = (((tt) << 2) + ((h) << 1));                                \
        int b_ = (tt) & 1;                                                    \
        gload_lds16(ga + (size_t)blk_ * 4096 + tid * 8,                       \
                    &As[b_][(h) << 1][wid * 512]);                            \
        gload_lds16(gb + (size_t)blk_ * 4096 + tid * 8,                       \
                    &Bs[b_][(h) << 1][wid * 512]);                            \
        gload_lds16(ga + (size_t)(blk_ + 1) * 4096 + tid * 8,                 \
                    &As[b_][((h) << 1) + 1][wid * 512]);                      \
        gload_lds16(gb + (size_t)(blk_ + 1) * 4096 + tid * 8,                 \
                    &Bs[b_][((h) << 1) + 1][wid * 512]);                      \
    } while (0)

    // prologue: stage tile 0 (both K-halves)
    STAGE(0, 0);
    STAGE(0, 1);

    for (int t = 0; t < nt; ++t) {
        const int cur = t & 1;
        #pragma unroll
        for (int p = 0; p < 2; ++p) {
            if (t + 1 < nt) {
                STAGE(t + 1, p);
                asm volatile("s_waitcnt vmcnt(8)" ::: "memory");
            } else if (p == 0) {
                asm volatile("s_waitcnt vmcnt(4)" ::: "memory");
            } else {
                asm volatile("s_waitcnt vmcnt(0)" ::: "memory");
            }
            __builtin_amdgcn_s_barrier();
            __builtin_amdgcn_sched_barrier(0);   // pin ds_reads below barrier

            const short* Ak = &As[cur][p * 2][0];
            const short* Bk = &Bs[cur][p * 2][0];

            bf16x8_t av[8], bv[4];
            #pragma unroll
            for (int n = 0; n < 4; ++n)
                bv[n] = *(const bf16x8_t*)&Bk[lsel + brow + n * 256];
            #pragma unroll
            for (int m = 0; m < 8; ++m)
                av[m] = *(const bf16x8_t*)&Ak[lsel + arow + m * 256];

            __builtin_amdgcn_s_setprio(1);
            #pragma unroll
            for (int m = 0; m < 8; ++m)
                #pragma unroll
                for (int n = 0; n < 4; ++n)
                    acc[m][n] = __builtin_amdgcn_mfma_f32_16x16x32_bf16(
                        av[m], bv[n], acc[m][n], 0, 0, 0);
            __builtin_amdgcn_s_setprio(0);
        }
    }
#undef STAGE

    int row_base = bm * BM2 + wr * 128;
    int col_base = bn * BN2 + wc * 64;
    #pragma unroll
    for (int n = 0; n < 4; ++n) {
        int col = col_base + n * 16 + fr;
        float sc = scales[col], bi = bias[col];
        #pragma unroll
        for (int m = 0; m < 8; ++m) {
            int m0 = row_base + m * 16 + fq * 4;
            #pragma unroll
            for (int r2 = 0; r2 < 4; ++r2)
                Y[(size_t)(m0 + r2) * N + col] = acc[m][n][r2] * sc + bi;
        }
    }
}

// ---------- fallback (if ws too small / odd dims): tiled fp32, inline dequant --

__global__ __launch_bounds__(256) void qlin_fallback(
    const float* __restrict__ x, const int* __restrict__ pw,
    const float* __restrict__ scales, const float* __restrict__ bias,
    float* __restrict__ Y, int M, int N, int K)
{
    __shared__ float Xs[64][32];
    __shared__ float Ws[64][33];
    int bn = blockIdx.x, bm = blockIdx.y;
    int tid = threadIdx.x;
    int tr = tid >> 4, tc = tid & 15;
    float acc[4][4] = {};
    int K2 = K >> 1;
    for (int kt = 0; kt < K; kt += 32) {
        #pragma unroll
        for (int u = 0; u < 8; ++u) {
            int idx = u * 256 + tid;
            int rr = idx >> 5, cc = idx & 31;
            Xs[rr][cc] = x[(size_t)(bm * 64 + rr) * K + kt + cc];
        }
        #pragma unroll
        for (int u = 0; u < 4; ++u) {
            int idx = u * 256 + tid;
            int rr = idx >> 4, cc = idx & 15;
            int v = pw[(size_t)(bn * 64 + rr) * K2 + (kt >> 1) + cc];
            Ws[rr][cc * 2]     = (float)((v & 15) - 8);
            Ws[rr][cc * 2 + 1] = (float)(((v >> 4) & 15) - 8);
        }
        __syncthreads();
        #pragma unroll 8
        for (int kk = 0; kk < 32; ++kk) {
            float xv[4], wv[4];
            #pragma unroll
            for (int i = 0; i < 4; ++i) xv[i] = Xs[tr * 4 + i][kk];
            #pragma unroll
            for (int j = 0; j < 4; ++j) wv[j] = Ws[tc * 4 + j][kk];
            #pragma unroll
            for (int i = 0; i < 4; ++i)
                #pragma unroll
                for (int j = 0; j < 4; ++j)
                    acc[i][j] += xv[i] * wv[j];
        }
        __syncthreads();
    }
    #pragma unroll
    for (int j = 0; j < 4; ++j) {
        int n = bn * 64 + tc * 4 + j;
        float sc = scales[n], bi = bias[n];
        #pragma unroll
        for (int i = 0; i < 4; ++i) {
            int m = bm * 64 + tr * 4 + i;
            Y[(size_t)m * N + n] = acc[i][j] * sc + bi;
        }
    }
}

// ---------- host ----------

extern "C" void kernel_launch(void* const* d_in, const int* in_sizes, int n_in,
                              void* d_out, int out_size, void* d_ws, size_t ws_size,
                              hipStream_t stream) {
    const float* x      = (const float*)d_in[0];
    const int*   pw     = (const int*)d_in[1];
    const float* scales = (const float*)d_in[2];
    const float* bias   = (const float*)d_in[3];
    float*       y      = (float*)d_out;

    int N = in_sizes[2];                         // 11008
    long long pwe = in_sizes[1];                 // N*K/2
    int K = (int)((2 * pwe) / N);                // 4096
    int M = in_sizes[0] / K;                     // 4096

    size_t xb_bytes = (size_t)M * K * 2;
    size_t wb_bytes = (size_t)N * K * 2;

    bool fits = (ws_size >= xb_bytes + wb_bytes);
    bool dims_ok = (M % 256 == 0) && (N % 256 == 0) && (K % 64 == 0) && (K >= 128);

    if (fits && dims_ok) {
        short* xb = (short*)d_ws;
        short* wb = (short*)((char*)d_ws + xb_bytes);
        int cpr = K / 8;                         // 16B chunks per row
        int nkt = K / 64;
        int ncx = (int)((size_t)M * K / 8);
        hipLaunchKernelGGL(cvt_x_kernel, dim3(2048), dim3(256), 0, stream,
                           (const float4*)x, (uint4*)xb, ncx, cpr, nkt);
        int ncw = (int)(pwe / 4);                // = N*K/8
        hipLaunchKernelGGL(dequant_w_kernel, dim3(2048), dim3(256), 0, stream,
                           (const int4*)pw, (uint4*)wb, ncw, cpr, nkt);
        int nwg = (M / 256) * (N / 256);
        hipLaunchKernelGGL(qlin_gemm256, dim3(nwg), dim3(512), 0, stream,
                           xb, wb, scales, bias, y, M, N, K);
    } else {
        hipLaunchKernelGGL(qlin_fallback, dim3(N / 64, M / 64), dim3(256), 0, stream,
                           x, pw, scales, bias, y, M, N, K);
    }
}